// Round 7
// baseline (141.933 us; speedup 1.0000x reference)
//
#include <hip/hip_runtime.h>
#include <hip/hip_bf16.h>
#include <math.h>

#define B_N 512
#define C_N 100000
#define CPAD 100032          // padded to multiple of 64
#define D_N 128
#define NCHUNK (CPAD / 64)   // 1563 = 256*6 + 27
#define K6_GX 256
#define K6_BLOCKS K6_GX
// each proxy pad row (zero vector) contributes exp(-18) to every row's sumexp
#define PAD_CORR (32.0f * 1.522998e-8f)

typedef short short8 __attribute__((ext_vector_type(8)));
typedef float f32x4 __attribute__((ext_vector_type(4)));

__device__ __forceinline__ unsigned short f2bf(float f) {
  unsigned int u = __float_as_uint(f);
  u += 0x7fffu + ((u >> 16) & 1u);
  return (unsigned short)(u >> 16);
}

__device__ __forceinline__ unsigned int pk2bf(float lo, float hi) {
  return (unsigned int)f2bf(lo) | ((unsigned int)f2bf(hi) << 16);
}

__device__ __forceinline__ void gl_lds16(const void* g, void* l) {
  __builtin_amdgcn_global_load_lds(
      (const __attribute__((address_space(1))) void*)g,
      (__attribute__((address_space(3))) void*)l, 16, 0, 0);
}

// full 64-lane wave sum via 6 shfl_xor steps
__device__ __forceinline__ float wave_sum(float v) {
#pragma unroll
  for (int off = 1; off < 64; off <<= 1) v += __shfl_xor(v, off);
  return v;
}

template <int NT>
__device__ __forceinline__ float block_reduce_sum(float v, float* red) {
  int t = threadIdx.x;
  __syncthreads();
  red[t] = v;
  __syncthreads();
#pragma unroll
  for (int s = NT / 2; s > 0; s >>= 1) {
    if (t < s) red[t] += red[t + s];
    __syncthreads();
  }
  return red[0];
}

// kX: X-normalize + Pb gather-normalize + diag. R7: shfl-based reductions
// (3 barriers total; the old block_reduce trees cost 21 __syncthreads for a
// 2-wave latency-bound kernel).
__global__ __launch_bounds__(128) void kX(const float* __restrict__ X,
                                          const float* __restrict__ proxies,
                                          const int* __restrict__ T,
                                          float* __restrict__ Xn, float* __restrict__ Pb,
                                          float* __restrict__ diagv,
                                          int* __restrict__ ctrs) {
  __shared__ float ra[2], rb[2], rc[2];
  int b = blockIdx.x;
  int t = threadIdx.x;
  int w = t >> 6, lane = t & 63;
  float v = X[b * D_N + t];
  int row = T[b];
  float p = proxies[(size_t)row * D_N + t];
  float wsx = wave_sum(v * v);
  float wsp = wave_sum(p * p);
  if (lane == 0) { ra[w] = wsx; rb[w] = wsp; }
  __syncthreads();
  float xn = v / fmaxf(sqrtf(ra[0] + ra[1]), 1e-12f);
  float pn = p / fmaxf(sqrtf(rb[0] + rb[1]), 1e-12f);
  Xn[b * D_N + t] = xn;
  Pb[b * D_N + t] = pn;
  float wd = wave_sum(pn * xn);
  if (lane == 0) rc[w] = wd;
  __syncthreads();
  if (t == 0) {
    diagv[b] = rc[0] + rc[1];
    if (b == 0) ctrs[32] = 0;  // k6 arrive counter, own cache line
  }
}

// k3: A[b,k] = relu(0.5*(Pb[b].Xn[k]+diag[k])) + relu(Xn[b].Xn[k]); S[b]=row sum.
// R7: 256 threads, 2 columns/thread (k=t, t+256) with 4 interleaved
// accumulators (2x loads in flight/wave, half the wave-launch count), and
// shfl-based rowsum (2 barriers vs 10).
__global__ __launch_bounds__(256) void k3_att(const float* __restrict__ Xn,
                                              const float* __restrict__ Pb,
                                              const float* __restrict__ diagv,
                                              float* __restrict__ A, float* __restrict__ S) {
  __shared__ float xb[128], pbv[128];
  __shared__ float r4[4];
  int b = blockIdx.x, t = threadIdx.x;
  int w = t >> 6, lane = t & 63;
  if (t < 128) {
    xb[t] = Xn[b * D_N + t];
    pbv[t] = Pb[b * D_N + t];
  }
  __syncthreads();
  const float4* xr0 = (const float4*)(Xn + (size_t)t * D_N);
  const float4* xr1 = (const float4*)(Xn + (size_t)(t + 256) * D_N);
  float d1a = 0.f, d2a = 0.f, d1b = 0.f, d2b = 0.f;
#pragma unroll
  for (int i = 0; i < 32; i++) {
    float4 u = xr0[i];
    float4 v = xr1[i];
    float p0 = pbv[4 * i], p1 = pbv[4 * i + 1], p2 = pbv[4 * i + 2], p3 = pbv[4 * i + 3];
    float x0 = xb[4 * i], x1 = xb[4 * i + 1], x2 = xb[4 * i + 2], x3 = xb[4 * i + 3];
    d1a += p0 * u.x + p1 * u.y + p2 * u.z + p3 * u.w;
    d2a += x0 * u.x + x1 * u.y + x2 * u.z + x3 * u.w;
    d1b += p0 * v.x + p1 * v.y + p2 * v.z + p3 * v.w;
    d2b += x0 * v.x + x1 * v.y + x2 * v.z + x3 * v.w;
  }
  float aa = fmaxf(0.5f * (d1a + diagv[t]), 0.f) + fmaxf(d2a, 0.f);
  float ab = fmaxf(0.5f * (d1b + diagv[t + 256]), 0.f) + fmaxf(d2b, 0.f);
  A[(size_t)b * B_N + t] = aa;
  A[(size_t)b * B_N + t + 256] = ab;
  float ws = wave_sum(aa + ab);
  if (lane == 0) r4[w] = ws;
  __syncthreads();
  if (t == 0) S[b] = r4[0] + r4[1] + r4[2] + r4[3];
}

// k4ab: fused k4a+k4b. Block b owns row b: aw[k]=A[b,k]/(S[k]+eps) in LDS,
// X2row = Xn[b,:] + aw @ Xn, renorm -> Xsb bf16, lossT[b], zero k6 state.
// R7: shfl-based renorm reductions (3 barriers vs ~20).
__global__ __launch_bounds__(512) void k4ab(const float* __restrict__ Xn,
                                            const float* __restrict__ Pb,
                                            const float* __restrict__ A,
                                            const float* __restrict__ S,
                                            unsigned short* __restrict__ Xsb,
                                            float* __restrict__ lossT,
                                            float* __restrict__ sumexpP) {
  __shared__ float xb[128], pbv[128];
  __shared__ float aw[512];
  __shared__ float red[512];
  __shared__ float r8a[8], r8b[8];
  int b = blockIdx.x, t = threadIdx.x;
  int w = t >> 6, lane = t & 63;
  if (t < 128) {
    xb[t] = Xn[b * D_N + t];
    pbv[t] = Pb[b * D_N + t];
  }
  aw[t] = A[(size_t)b * B_N + t] / (S[t] + 1e-5f);
  __syncthreads();

  // matvec: 4 k-quarters x 128 dims; 4 accumulators break the FMA dep chain
  int d = t & 127, h = t >> 7;
  const float* xp = Xn + (size_t)(128 * h) * D_N + d;
  const float* awp = aw + 128 * h;
  float a0 = 0.f, a1 = 0.f, a2 = 0.f, a3 = 0.f;
#pragma unroll 8
  for (int kk = 0; kk < 128; kk += 4) {
    a0 = fmaf(awp[kk], xp[(size_t)kk * D_N], a0);
    a1 = fmaf(awp[kk + 1], xp[(size_t)(kk + 1) * D_N], a1);
    a2 = fmaf(awp[kk + 2], xp[(size_t)(kk + 2) * D_N], a2);
    a3 = fmaf(awp[kk + 3], xp[(size_t)(kk + 3) * D_N], a3);
  }
  red[t] = (a0 + a1) + (a2 + a3);
  __syncthreads();
  float x2 = (t < 128) ? (xb[t] + red[t] + red[t + 128] + red[t + 256] + red[t + 384]) : 0.f;

  // renorm via wave reductions (x2 == 0 for t >= 128, so full-block sum is ok)
  float wss = wave_sum(x2 * x2);
  if (lane == 0) r8a[w] = wss;
  __syncthreads();
  float ss = 0.f;
#pragma unroll
  for (int i = 0; i < 8; i++) ss += r8a[i];
  float xs = 3.f * x2 / fmaxf(sqrtf(ss), 1e-12f);
  if (t < 128) Xsb[b * D_N + t] = f2bf(xs);
  float wdt = wave_sum((t < 128) ? xs * pbv[t] : 0.f);
  if (lane == 0) r8b[w] = wdt;
  __syncthreads();
  if (t == 0) {
    float dt = 0.f;
#pragma unroll
    for (int i = 0; i < 8; i++) dt += r8b[i];
    lossT[b] = fmaxf(18.f - 6.f * dt, 0.f);
    sumexpP[b * 16] = 0.f;
  }
}

// K6: Dm[b,c] = max(18 - 6*dot(Xs[b], Pn[c]), 0); sumexp[b] += sum_c exp(-Dm).
// Unchanged from R6 (proven): fused f32 staging + in-loop normalize/convert,
// sP double-buffer with ONE barrier per chunk, per-nt MFMA/exp pipeline,
// contiguous chunk ranges.
__global__ __launch_bounds__(512, 2) void k6_big(const float* __restrict__ proxies,
                                                 const unsigned short* __restrict__ Xsb,
                                                 float* __restrict__ sumexpP,
                                                 const float* __restrict__ lossT,
                                                 int* __restrict__ ctrs,
                                                 float* __restrict__ out) {
  __shared__ __align__(16) float fP[2][64 * 128];           // 2 x 32 KB raw f32 staging
  __shared__ __align__(16) unsigned short sP[2][64 * 128];  // 2 x 16 KB bf16, swizzled
  __shared__ float redf[512];
  __shared__ int sLast;
  const int t = threadIdx.x;
  const int w = t >> 6;        // 0..7
  const int lane = t & 63;
  const int lc = lane & 15;
  const int q = lane >> 4;

  // A-fragments once from global bf16 Xsb: wave w owns m-rows 64w..64w+63
  short8 afr[4][4];
#pragma unroll
  for (int mt = 0; mt < 4; mt++)
#pragma unroll
    for (int ks = 0; ks < 4; ks++)
      afr[mt][ks] = *(const short8*)(Xsb + (size_t)(64 * w + 16 * mt + lc) * D_N +
                                     ks * 32 + q * 8);

  float pe[4][4];
#pragma unroll
  for (int mt = 0; mt < 4; mt++)
#pragma unroll
    for (int r = 0; r < 4; r++) pe[mt][r] = 0.f;

  // f32 staging: wave w stages rows 8w..8w+7 linearly (4 instr x 1024 B =
  // 2 rows each). Per lane: row += lane>>5, 16B granule at col (lane&31)*4.
  const int srow = 8 * w + (lane >> 5);
  const int scol = (lane & 31) * 4;
#define STAGEF(c0_, buf_)                                                             \
  {                                                                                   \
    _Pragma("unroll") for (int j = 0; j < 4; j++) {                                   \
      int gr = (c0_) + srow + 2 * j;                                                  \
      gr = gr < C_N ? gr : (C_N - 1); /* clamp pad rows: no OOB fault */              \
      gl_lds16(proxies + (size_t)gr * D_N + scol,                                     \
               &fP[buf_][(8 * w + 2 * j) * D_N]);                                     \
    }                                                                                 \
  }

  // convert-pass geometry: thread handles row cr=t>>3, cols 16*cs..16*cs+15
  const int cr = t >> 3;
  const int cs = t & 7;

  // contiguous chunk range: block i -> start 6i+min(i,27), count 6+(i<27)
  const int bid = blockIdx.x;
  const int start = bid * 6 + (bid < 27 ? bid : 27);
  const int nch = 6 + (bid < 27 ? 1 : 0);

  STAGEF(start * 64, 0);
  int fbuf = 0, sbuf = 0;
  for (int k = 0; k < nch; k++) {
    const int cc = start + k;
    if (k + 1 < nch) {
      STAGEF((cc + 1) * 64, fbuf ^ 1);     // issue next-buffer DMA early
      __builtin_amdgcn_sched_barrier(0);   // keep stage issue above the wait
      __builtin_amdgcn_s_waitcnt(0x0F74);  // vmcnt<=4: current landed, next in flight
    } else {
      __builtin_amdgcn_sched_barrier(0);
      __builtin_amdgcn_s_waitcnt(0x0F70);  // last chunk: drain
    }
    __builtin_amdgcn_sched_barrier(0);

    // ---- wave-local normalize + bf16 convert into swizzled sP[sbuf] ----
    // (fP rows 8w..8w+7 were staged by THIS wave.)
    {
      const float* src = &fP[fbuf][cr * D_N + cs * 16];
      float4 v0 = ((const float4*)src)[0];
      float4 v1 = ((const float4*)src)[1];
      float4 v2 = ((const float4*)src)[2];
      float4 v3 = ((const float4*)src)[3];
      float s0 = v0.x * v0.x + v0.y * v0.y + v0.z * v0.z + v0.w * v0.w;
      float s1 = v1.x * v1.x + v1.y * v1.y + v1.z * v1.z + v1.w * v1.w;
      float s2 = v2.x * v2.x + v2.y * v2.y + v2.z * v2.z + v2.w * v2.w;
      float s3 = v3.x * v3.x + v3.y * v3.y + v3.z * v3.z + v3.w * v3.w;
      float ss = (s0 + s1) + (s2 + s3);  // balanced tree: matches old kA bit-exactly
      ss += __shfl_xor(ss, 1);
      ss += __shfl_xor(ss, 2);
      ss += __shfl_xor(ss, 4);
      float inv = 1.f / fmaxf(sqrtf(ss), 1e-12f);
      if (cc * 64 + cr >= C_N) inv = 0.f;  // pad rows -> exact zero vectors
      uint4 g0, g1;
      g0.x = pk2bf(v0.x * inv, v0.y * inv);
      g0.y = pk2bf(v0.z * inv, v0.w * inv);
      g0.z = pk2bf(v1.x * inv, v1.y * inv);
      g0.w = pk2bf(v1.z * inv, v1.w * inv);
      g1.x = pk2bf(v2.x * inv, v2.y * inv);
      g1.y = pk2bf(v2.z * inv, v2.w * inv);
      g1.z = pk2bf(v3.x * inv, v3.y * inv);
      g1.w = pk2bf(v3.z * inv, v3.w * inv);
      int P0 = (2 * cs) ^ (cr & 15);      // bank swizzle: phys granule = logical ^ (row&15)
      int P1 = (2 * cs + 1) ^ (cr & 15);
      *(uint4*)&sP[sbuf][cr * D_N + P0 * 8] = g0;
      *(uint4*)&sP[sbuf][cr * D_N + P1 * 8] = g1;
    }
    __builtin_amdgcn_s_waitcnt(0xC07F);  // lgkmcnt(0): own ds ops drained
    __builtin_amdgcn_s_barrier();        // sP[sbuf] tile ready for all waves
    __builtin_amdgcn_sched_barrier(0);   // no ds_read hoist above barrier

    // ---- per-nt pipeline: ds_reads -> MFMA -> exp epilogue, 4x ----
#pragma unroll
    for (int nt = 0; nt < 4; nt++) {
      short8 bfr[4];
#pragma unroll
      for (int ks = 0; ks < 4; ks++) {
        int R = 16 * nt + lc;
        int g = (ks * 4 + q) ^ lc;  // R&15 == lc
        bfr[ks] = *(const short8*)(&sP[sbuf][R * 128 + (g << 3)]);
      }
      f32x4 acc[4];
#pragma unroll
      for (int mt = 0; mt < 4; mt++) acc[mt] = (f32x4){0.f, 0.f, 0.f, 0.f};
#pragma unroll
      for (int ks = 0; ks < 4; ks++)
#pragma unroll
        for (int mt = 0; mt < 4; mt++)
          acc[mt] = __builtin_amdgcn_mfma_f32_16x16x32_bf16(afr[mt][ks], bfr[ks],
                                                            acc[mt], 0, 0, 0);
      // exp(min(6a-18,0)) == exp2(min((6*log2e)a - 18*log2e, 0)), log2e in FMA.
#pragma unroll
      for (int mt = 0; mt < 4; mt++)
#pragma unroll
        for (int r = 0; r < 4; r++)
          pe[mt][r] += __builtin_amdgcn_exp2f(
              fminf(__fmaf_rn(8.65617024533378f, acc[mt][r], -25.9685107360013f), 0.f));
    }
    // no release barrier: next convert targets sP[sbuf^1]; two-iter reuse of
    // sP[sbuf] is fenced by each wave's lgkmcnt(0)+barrier (see header note).
    fbuf ^= 1;
    sbuf ^= 1;
  }

  // reduce over 16 col-lanes; one padded atomic per row
#pragma unroll
  for (int mt = 0; mt < 4; mt++) {
#pragma unroll
    for (int r = 0; r < 4; r++) {
      float p = pe[mt][r];
      p += __shfl_xor(p, 1);
      p += __shfl_xor(p, 2);
      p += __shfl_xor(p, 4);
      p += __shfl_xor(p, 8);
      if (lc == 0) {
        int rb = 64 * w + 16 * mt + 4 * q + r;
        atomicAdd(&sumexpP[rb * 16], p);
      }
    }
  }

  // fused k7: last block to arrive reduces the loss. Atomics complete at the
  // device coherence point; ordering needs only vmcnt(0) (NO threadfence --
  // agent fences emit L2 writeback/invalidate, measured ~46 us over the grid).
  __builtin_amdgcn_s_waitcnt(0);
  if (t == 0) sLast = atomicAdd(&ctrs[32], 1);
  __syncthreads();
  if (sLast == K6_BLOCKS - 1) {
    float se = __hip_atomic_load(&sumexpP[t * 16], __ATOMIC_RELAXED,
                                 __HIP_MEMORY_SCOPE_AGENT);
    float v = lossT[t] + logf(se - PAD_CORR);
    float s = block_reduce_sum<512>(v, redf);
    if (t == 0) out[0] = s * (1.0f / 512.0f);
  }
}

extern "C" void kernel_launch(void* const* d_in, const int* in_sizes, int n_in,
                              void* d_out, int out_size, void* d_ws, size_t ws_size,
                              hipStream_t stream) {
  const float* X = (const float*)d_in[0];
  const int* T = (const int*)d_in[2];
  const float* proxies = (const float*)d_in[3];
  float* out = (float*)d_out;

  char* ws = (char*)d_ws;
  // (Pnb region retired -- offsets kept identical for layout stability)
  float* Xn = (float*)(ws + (size_t)CPAD * D_N * 2);       // 512*128
  float* Pb = Xn + B_N * D_N;                              // 512*128
  float* X2 = Pb + B_N * D_N;                              // 512*128 (unused, layout kept)
  float* dg = X2 + B_N * D_N;                              // 512
  float* S = dg + B_N;                                     // 512
  float* lossT = S + B_N;                                  // 512
  float* sumexpP = lossT + B_N;                            // 512*16 (line-padded)
  unsigned short* Xsb = (unsigned short*)(sumexpP + B_N * 16);  // 512*128 bf16
  float* A = (float*)(Xsb + B_N * D_N);                    // 512*512
  int* ctrs = (int*)(A + B_N * B_N);                       // [32] = k6 arrive counter

  kX<<<B_N, 128, 0, stream>>>(X, proxies, T, Xn, Pb, dg, ctrs);
  k3_att<<<B_N, 256, 0, stream>>>(Xn, Pb, dg, A, S);
  k4ab<<<B_N, 512, 0, stream>>>(Xn, Pb, A, S, Xsb, lossT, sumexpP);
  k6_big<<<K6_GX, 512, 0, stream>>>(proxies, Xsb, sumexpP, lossT, ctrs, out);
}